// Round 8
// baseline (147.328 us; speedup 1.0000x reference)
//
#include <hip/hip_runtime.h>
#include <hip/hip_bf16.h>
#include <math.h>

#define BB 256
#define NN 256
#define DIN 128
#define NH 4
#define DH 32
#define HID 128   // NH*DH
#define NEG 0.2f
#define LN_EPS 1e-5f
#define L2E 1.44269504f

typedef __attribute__((ext_vector_type(8))) short short8;
typedef __attribute__((ext_vector_type(4))) float float4v;
typedef __attribute__((ext_vector_type(2))) unsigned int uint2v;
typedef __attribute__((ext_vector_type(4))) unsigned int uint4v;

// round-half-up bf16 cast (2 ops)
__device__ __forceinline__ short f2bs(float f) {
    return (short)((__float_as_uint(f) + 0x8000u) >> 16);
}
// pack two floats -> two bf16 in one uint (2 add + 1 perm)
__device__ __forceinline__ unsigned int pack2(float a, float b) {
    return __builtin_amdgcn_perm(__float_as_uint(b) + 0x8000u,
                                 __float_as_uint(a) + 0x8000u, 0x07060302u);
}

#define MFMA16(a, b, c) __builtin_amdgcn_mfma_f32_16x16x32_bf16(a, b, c, 0, 0, 0)

// ---------------------------------------------------------------------------
// Prep: W1T bf16 + att-projected GEMM rows, computed ONCE (not per block).
// blocks 0-63: W1Tg[n][k] = bf16(W1[k][n]); blocks 64-67: awTg[rr][k].
// ---------------------------------------------------------------------------
__global__ __launch_bounds__(256) void k_prep(
    const float* __restrict__ W1, const float* __restrict__ as1,
    const float* __restrict__ ad1, short* __restrict__ W1Tg,
    short* __restrict__ awTg)
{
    const int blk = blockIdx.x;
    if (blk < 64) {
        const int idx = blk * 256 + threadIdx.x;     // n*128 + k
        const int n = idx >> 7, k = idx & 127;
        W1Tg[idx] = f2bs(W1[k * HID + n]);           // coalesced writes
    } else {
        const int id = (blk - 64) * 256 + threadIdx.x;  // 1024
        const int rr = id >> 7, k = id & 127;
        const int hh = rr & 3;
        const float* att = ((rr & 4) ? ad1 : as1) + hh * 32;
        const float* wrow = W1 + k * HID + hh * 32;
        float acc = 0.f;
#pragma unroll
        for (int e = 0; e < 8; ++e) {
            const float4v wv = *(const float4v*)(wrow + e * 4);
            const float4v av = *(const float4v*)(att + e * 4);
            acc += wv[0] * av[0] + wv[1] * av[1] + wv[2] * av[2] + wv[3] * av[3];
        }
        awTg[rr * DIN + k] = f2bs(acc * L2E);        // log2-scaled
    }
}

// ---------------------------------------------------------------------------
// One block per batch element, 1024 threads = 16 waves (4/SIMD).
// Identities:
//   2^lrelu(d'+s') = 2^{0.2d'} * [ Bp_j * max(R_i*S_j, 1) ]
//     (R=2^{0.8d'}, S=2^{0.8s'}, Bp=2^{0.2s'}); per-i scale cancels in softmax
//   -> per weight: pk_mul, pk_max(1.0), pk_mul, pack. No per-i exp pair,
//      no max-shift. Same trick (base e) in the layer-2 scalar attention.
// ---------------------------------------------------------------------------
__global__ __launch_bounds__(1024, 4) void k_mega(
    const float* __restrict__ x, const short* __restrict__ W1Tg,
    const short* __restrict__ awTg,
    const float* __restrict__ b1, const float* __restrict__ gamma,
    const float* __restrict__ beta, const float* __restrict__ W2,
    const float* __restrict__ bias2, const float* __restrict__ att_src2,
    const float* __restrict__ att_dst2, float* __restrict__ out)
{
    const int b = blockIdx.x, t = threadIdx.x;
    const int w = t >> 6, lane = t & 63;
    const int l16 = lane & 15, q = lane >> 4;

    __shared__ short uA[34816];          // xs[256][136] -> hT[128][264]
    __shared__ short W1Ts[128 * 136];    // dead after phase 1
    __shared__ short awT[16 * 136];      // rows 0-3 src heads, 4-7 dst heads
    __shared__ float Sj[NH][NN] __attribute__((aligned(16)));
    __shared__ float Bpj[NH][NN] __attribute__((aligned(16)));
    __shared__ float ssraw[NH][NN], ddlog[NH][NN];
    __shared__ float b1s[HID], gws[HID], bws[HID];
    __shared__ float part[NH][NN * 3];   // phase-2 LN partials; reused phase 4
    __shared__ float Ssc[2];
    __shared__ float h2v[NN] __attribute__((aligned(16)));
    __shared__ float Tjt[NN] __attribute__((aligned(16)));
    __shared__ float Ept[NN] __attribute__((aligned(16)));

    // ---- Phase 0: stage x (bf16), W1Ts + awT from precomputed global ----
    const float* xb = x + (size_t)b * NN * DIN;
#pragma unroll
    for (int it = 0; it < 8; ++it) {
        const int idx = t + it * 1024;           // 8192 float4s
        const int row = idx >> 5, c4 = idx & 31;
        const float4v v = ((const float4v*)xb)[idx];
        uint2v p;
        p[0] = pack2(v[0], v[1]);
        p[1] = pack2(v[2], v[3]);
        *(uint2v*)&uA[row * 136 + c4 * 4] = p;
    }
    {   // W1Ts: 2 coalesced b128 copies per thread
        const int n = t >> 3, k0 = (t & 7) * 16;
        const uint4v a = *(const uint4v*)&W1Tg[n * DIN + k0];
        const uint4v c = *(const uint4v*)&W1Tg[n * DIN + k0 + 8];
        *(uint4v*)&W1Ts[n * 136 + k0] = a;
        *(uint4v*)&W1Ts[n * 136 + k0 + 8] = c;
    }
    {   // awT: one u16 per thread
        const int rr = t >> 7, k = t & 127;
        awT[rr * 136 + k] = awTg[rr * DIN + k];
    }
    if (t < HID) {
        b1s[t] = b1[t];
        const float w2v = W2[t];
        gws[t] = gamma[t] * w2v;
        bws[t] = beta[t] * w2v;
    }
    __syncthreads();

    // ---- Phase 1: hT = W1T @ x^T (+ augmented att rows on waves 0/15) ----
    const int dtile = w & 7, jhalf = w >> 3;
    const bool isaug = (w == 0) || (w == 15);
    float4v acc1[8], accA[8];
#pragma unroll
    for (int i = 0; i < 8; ++i) {
        acc1[i] = (float4v){0.f, 0.f, 0.f, 0.f};
        accA[i] = (float4v){0.f, 0.f, 0.f, 0.f};
    }
    const short* arow = &W1Ts[(dtile * 16 + l16) * 136];
    const short* arow2 = &awT[l16 * 136];
#pragma unroll
    for (int ks = 0; ks < 4; ++ks) {
        const short8 afr = *(const short8*)&arow[ks * 32 + q * 8];
        short8 afr2;
        if (isaug) afr2 = *(const short8*)&arow2[ks * 32 + q * 8];
#pragma unroll
        for (int nt = 0; nt < 8; ++nt) {
            const short8 bfr = *(const short8*)&uA[((jhalf * 8 + nt) * 16 + l16) * 136 + ks * 32 + q * 8];
            acc1[nt] = MFMA16(afr, bfr, acc1[nt]);
            if (isaug) accA[nt] = MFMA16(afr2, bfr, accA[nt]);
        }
    }
    // raw attention coeffs (log2-scaled) from the augmented tile
    if (isaug && q < 2) {
        float (*dstA)[NN] = (q == 0) ? ssraw : ddlog;   // rows 0-3 src, 4-7 dst
#pragma unroll
        for (int nt = 0; nt < 8; ++nt)
#pragma unroll
            for (int r = 0; r < 4; ++r)
                dstA[r][jhalf * 128 + nt * 16 + l16] = accA[nt][r];
    }
    __syncthreads();   // xs + W1Ts consumed; ssraw/ddlog published
#pragma unroll
    for (int nt = 0; nt < 8; ++nt)
#pragma unroll
        for (int r = 0; r < 4; ++r)
            uA[(dtile * 16 + q * 4 + r) * 264 + (jhalf * 8 + nt) * 16 + l16] = f2bs(acc1[nt][r]);
    {   // per-j tables: S = 2^{0.8 s'}, Bp = 2^{0.2 s'}
        const int hs = t >> 8, js = t & 255;
        const float vs = ssraw[hs][js];
        Sj[hs][js]  = exp2f(0.8f * vs);
        Bpj[hs][js] = exp2f(0.2f * vs);
    }
    __syncthreads();

    // ---- Phase 2: attention aggregation + in-register LN partials ----
    {
        if (w < 2) {   // LN scalars (consumed after next barrier)
            const float* src = (w == 0) ? gws : bws;
            float v = src[lane] + src[lane + 64];
#pragma unroll
            for (int m = 1; m < 64; m <<= 1) v += __shfl_xor(v, m, 64);
            if (lane == 0) Ssc[w] = v;
        }
        const int hh = w >> 2, qtr = w & 3;
        float R[4];
#pragma unroll
        for (int u = 0; u < 4; ++u)
            R[u] = exp2f(0.8f * ddlog[hh][qtr * 64 + u * 16 + l16]);
        float4v acc2[4][2], accL[4];
#pragma unroll
        for (int u = 0; u < 4; ++u) {
            acc2[u][0] = (float4v){0.f, 0.f, 0.f, 0.f};
            acc2[u][1] = (float4v){0.f, 0.f, 0.f, 0.f};
            accL[u]    = (float4v){0.f, 0.f, 0.f, 0.f};
        }
        short8 ones;
#pragma unroll
        for (int e = 0; e < 8; ++e) ones[e] = (short)0x3F80;
        const float4v one4 = {1.f, 1.f, 1.f, 1.f};

        const short* hTh = &uA[(hh * 32) * 264];
#pragma unroll 2
        for (int ks = 0; ks < 8; ++ks) {
            const short8 a0 = *(const short8*)&hTh[l16 * 264 + ks * 32 + q * 8];
            const short8 a1 = *(const short8*)&hTh[(16 + l16) * 264 + ks * 32 + q * 8];
            const float4v s0 = *(const float4v*)&Sj[hh][ks * 32 + q * 8];
            const float4v s1 = *(const float4v*)&Sj[hh][ks * 32 + q * 8 + 4];
            const float4v p0 = *(const float4v*)&Bpj[hh][ks * 32 + q * 8];
            const float4v p1 = *(const float4v*)&Bpj[hh][ks * 32 + q * 8 + 4];
#pragma unroll
            for (int u = 0; u < 4; ++u) {
                const float4v m0 = __builtin_elementwise_max(R[u] * s0, one4) * p0;
                const float4v m1 = __builtin_elementwise_max(R[u] * s1, one4) * p1;
                union { short8 s8; unsigned int u32[4]; } bfr;
                bfr.u32[0] = pack2(m0.x, m0.y);
                bfr.u32[1] = pack2(m0.z, m0.w);
                bfr.u32[2] = pack2(m1.x, m1.y);
                bfr.u32[3] = pack2(m1.z, m1.w);
                acc2[u][0] = MFMA16(a0, bfr.s8, acc2[u][0]);
                acc2[u][1] = MFMA16(a1, bfr.s8, acc2[u][1]);
                accL[u]    = MFMA16(ones, bfr.s8, accL[u]);
            }
        }
        // epilogue: normalize in registers, accumulate LN partials, reduce over q
        float b1r[8], gwr[8];
#pragma unroll
        for (int mt = 0; mt < 2; ++mt)
#pragma unroll
            for (int r = 0; r < 4; ++r) {
                const int d = hh * 32 + mt * 16 + q * 4 + r;
                b1r[mt * 4 + r] = b1s[d];
                gwr[mt * 4 + r] = gws[d];
            }
#pragma unroll
        for (int u = 0; u < 4; ++u) {
            const float inv = 1.f / accL[u][0];
            float s = 0.f, sq = 0.f, t3 = 0.f;
#pragma unroll
            for (int mt = 0; mt < 2; ++mt)
#pragma unroll
                for (int r = 0; r < 4; ++r) {
                    const float v = fmaf(acc2[u][mt][r], inv, b1r[mt * 4 + r]);
                    s += v;
                    sq = fmaf(v, v, sq);
                    t3 = fmaf(v, gwr[mt * 4 + r], t3);
                }
            s  += __shfl_xor(s, 16, 64);  s  += __shfl_xor(s, 32, 64);
            sq += __shfl_xor(sq, 16, 64); sq += __shfl_xor(sq, 32, 64);
            t3 += __shfl_xor(t3, 16, 64); t3 += __shfl_xor(t3, 32, 64);
            if (q == 0) {
                float* pp = &part[hh][(qtr * 64 + u * 16 + l16) * 3];
                pp[0] = s; pp[1] = sq; pp[2] = t3;
            }
        }
    }
    __syncthreads();

    // ---- Phase 3: finish LN + W2 dot; layer-2 per-j tables (base e) ----
    if (t < NN) {
        float s = 0.f, sq = 0.f, t3 = 0.f;
#pragma unroll
        for (int hh2 = 0; hh2 < 4; ++hh2) {
            const float* pp = &part[hh2][t * 3];
            s += pp[0]; sq += pp[1]; t3 += pp[2];
        }
        const float mu = s * (1.f / HID);
        const float var = sq * (1.f / HID) - mu * mu;
        const float rs = rsqrtf(var + LN_EPS);
        const float h2 = rs * (t3 - mu * Ssc[0]) + Ssc[1];
        h2v[t] = h2;
        const float e = h2 * att_src2[0];
        Tjt[t] = __expf(0.8f * e);
        Ept[t] = __expf(0.2f * e);
    }
    __syncthreads();

    // ---- Phase 4: layer-2 scalar attention + ELU (vectorized, no shift) ----
    {
        const int i3 = t & 255, hf = t >> 8;
        const float ed = h2v[i3] * att_dst2[0];
        const float Q = __expf(0.8f * ed);
        const float4v one4 = {1.f, 1.f, 1.f, 1.f};
        float4v l4 = {0.f, 0.f, 0.f, 0.f}, n4 = {0.f, 0.f, 0.f, 0.f};
#pragma unroll 4
        for (int jz = 0; jz < 16; ++jz) {
            const int j4 = (hf * 16 + jz) * 4;
            const float4v tv = *(const float4v*)&Tjt[j4];
            const float4v ev = *(const float4v*)&Ept[j4];
            const float4v hv = *(const float4v*)&h2v[j4];
            const float4v w4 = __builtin_elementwise_max(Q * tv, one4) * ev;
            l4 += w4;
            n4 += w4 * hv;
        }
        float l2  = (l4.x + l4.y) + (l4.z + l4.w);
        float num = (n4.x + n4.y) + (n4.z + n4.w);
        float* pw = &part[0][0];
        const int pb = (hf * 256 + i3) * 2;
        pw[pb] = l2; pw[pb + 1] = num;
        __syncthreads();
        if (hf == 0) {
#pragma unroll
            for (int k = 1; k < 4; ++k) {
                const int pk = (k * 256 + i3) * 2;
                l2 += pw[pk]; num += pw[pk + 1];
            }
            float o = num / l2 + bias2[0];
            o = (o > 0.f) ? o : (__expf(o) - 1.f);
            out[b * NN + i3] = o;
        }
    }
}

extern "C" void kernel_launch(void* const* d_in, const int* in_sizes, int n_in,
                              void* d_out, int out_size, void* d_ws, size_t ws_size,
                              hipStream_t stream) {
    const float* x   = (const float*)d_in[0];
    const float* W1  = (const float*)d_in[2];
    const float* b1  = (const float*)d_in[3];
    const float* as1 = (const float*)d_in[4];
    const float* ad1 = (const float*)d_in[5];
    const float* gam = (const float*)d_in[6];
    const float* bet = (const float*)d_in[7];
    const float* W2  = (const float*)d_in[8];
    const float* bi2 = (const float*)d_in[9];
    const float* as2 = (const float*)d_in[10];
    const float* ad2 = (const float*)d_in[11];
    float* out = (float*)d_out;

    short* W1Tg = (short*)d_ws;                       // 32 KB
    short* awTg = (short*)d_ws + DIN * HID;           // 2 KB

    k_prep<<<68, 256, 0, stream>>>(W1, as1, ad1, W1Tg, awTg);
    k_mega<<<BB, 1024, 0, stream>>>(x, W1Tg, awTg, b1, gam, bet, W2,
                                    bi2, as2, ad2, out);
}